// Round 9
// baseline (278.436 us; speedup 1.0000x reference)
//
#include <hip/hip_runtime.h>
#include <hip/hip_bf16.h>
#include <stdint.h>

typedef __attribute__((ext_vector_type(8))) short short8;
typedef __attribute__((ext_vector_type(4))) short short4v;
typedef __attribute__((ext_vector_type(4))) float f32x4;
typedef __attribute__((ext_vector_type(16))) float f32x16;

#define B_ 2
#define S_ 2048
#define D_ 1024
#define H_ 16
#define DK_ 64
#define M_ (B_*S_)   // 4096

// workspace layout (in shorts):
//   [0 .. 12582912)          Q | K | VT, each M_*D_ bf16 (VT is [B,H,DK,S])
//   [12582912 .. 16777216)   Xb  bf16 (M_*D_)
//   [16777216 .. 19922944)   Wqb|Wkb|Wvb bf16 (D_*D_ each)
#define WS_QKV   0
#define WS_XB    12582912
#define WS_WB    16777216

// softmax-in-base-2: fold 1/sqrt(DK) * log2(e) into Q
#define QSCALE (0.125f * 1.44269504088896f)

// async global->LDS, 16B per lane; lds base wave-uniform, lane i -> base + i*16
#define GLL16(g, l) __builtin_amdgcn_global_load_lds( \
    (const __attribute__((address_space(1))) void*)(g), \
    (__attribute__((address_space(3))) void*)(l), 16, 0, 0)

#define WAIT_VM0  asm volatile("s_waitcnt vmcnt(0)" ::: "memory")
#define WAIT_VM4  asm volatile("s_waitcnt vmcnt(4)" ::: "memory")
#define WAIT_VM8  asm volatile("s_waitcnt vmcnt(8)" ::: "memory")
#define WAIT_VM16 asm volatile("s_waitcnt vmcnt(16)" ::: "memory")
#define WAIT_LGKM0 asm volatile("s_waitcnt lgkmcnt(0)" ::: "memory")
#define BARRIER_RAW asm volatile("s_barrier" ::: "memory")

static __device__ __forceinline__ short f2bf(float f){
  union { float f; unsigned u; } x; x.f = f;
  unsigned r = x.u + 0x7fff + ((x.u >> 16) & 1);   // round-to-nearest-even
  return (short)(r >> 16);
}

// ---------------------------------------------------------------------------
// Kernel 0: downcast f32 inputs (X, Wq, Wk, Wv) to bf16 in workspace.
// ---------------------------------------------------------------------------
__global__ __launch_bounds__(256) void cvt_bf16(
    const float* __restrict__ X,  const float* __restrict__ Wq,
    const float* __restrict__ Wk, const float* __restrict__ Wv,
    short* __restrict__ ws)
{
  const int z = blockIdx.z;
  const float* src; short* dst; int n;
  if (z == 0)      { src = X;  dst = ws + WS_XB;               n = M_*D_; }
  else if (z == 1) { src = Wq; dst = ws + WS_WB;               n = D_*D_; }
  else if (z == 2) { src = Wk; dst = ws + WS_WB + D_*D_;       n = D_*D_; }
  else             { src = Wv; dst = ws + WS_WB + 2*(D_*D_);   n = D_*D_; }
  const int stride = gridDim.x * blockDim.x * 4;
  for (int i = (blockIdx.x * blockDim.x + threadIdx.x) * 4; i < n; i += stride) {
    float4 v = *(const float4*)(src + i);
    short4v o;
    o.x = f2bf(v.x); o.y = f2bf(v.y); o.z = f2bf(v.z); o.w = f2bf(v.w);
    *(short4v*)(dst + i) = o;
  }
}

// ---------------------------------------------------------------------------
// Kernel 1: QKV projection, 256x256 tile, BK=32 — R9: FOUR waves, each with a
// 128x128 per-wave tile (2M x 2N wave grid, 256 thr).
// Rationale: LDS->reg traffic per output element = (Mw+Nw)/(Mw*Nw); 128x128
// gives 1.0 B/elem vs 128x64's 1.5 -> block reads drop 96->64 b128/K-tile.
// R8's cross-tile register double-buffer retained (MFMAs have zero lgkm
// dependency; the 64 block-wide reads drain concurrently).
//   regs: acc 8x8xf32x4 = 256 + frags 2x16xshort8 = 128 -> ~430 VGPR,
//   1 wave/SIMD (launch_bounds(256,1); unified VGPR/AGPR file).
//   ledger (8 GLL/tile): prologue 32 GLL, vmcnt(16) retires tiles 0,1;
//   window kt stages tile kt+4 into buf kt&3 (readers drained: lgkm0 before
//   the prior barrier); end-of-window vmcnt(16) retires tile kt+2
//   (needed by window kt+1's NXT reads); tail 28->vm8, 29->vm0.
// ---------------------------------------------------------------------------
__global__ __launch_bounds__(256, 1) void qkv_gemm(
    const short* __restrict__ ws_in,
    const float* __restrict__ bq, const float* __restrict__ bk,
    const float* __restrict__ bv, short* __restrict__ qkv)
{
  const int z = blockIdx.z;
  const short* X  = ws_in + WS_XB;
  const short* Wm = ws_in + WS_WB + (size_t)z * (D_*D_);
  short* out = qkv + (size_t)z * (M_*D_);

  __shared__ __align__(16) short lds[65536];   // 4 bufs x (A 8192 | B 8192)

  const int t = threadIdx.x;            // 0..255
  const int w = t >> 6, lane = t & 63;  // 4 waves
  const int quad = lane >> 4, l16 = lane & 15;
  const int wm = w >> 1, wn = w & 1;    // wave grid 2(M) x 2(N)
  const int m0 = blockIdx.y * 256, n0 = blockIdx.x * 256;

  // staging: wave w, GLL j covers rows (w*4+j)*16 .. +16 of the 256-row
  // half; lane -> row (lane>>2), phys chunk lane&3; source logical chunk
  // (lane&3)^(row&3) (XOR involution, read-side swz below matches).
  const int rA  = lane >> 2;                       // 0..15
  const int slc = ((lane & 3) ^ (rA & 3)) * 8;     // swizzled src chunk
  const short* sA = X  + (size_t)(m0 + w*64 + rA) * D_ + slc;
  const short* sB = Wm + (size_t)(n0 + w*64 + rA) * D_ + slc;
  const int dA = w*2048;                // lds dest base (shorts) for A GLLs

  const int swz = quad ^ (l16 & 3);     // read-side swizzle
  int aoff[8], boff[8];
  #pragma unroll
  for (int mf=0; mf<8; mf++) aoff[mf] = (wm*128 + mf*16 + l16)*32 + swz*8;
  #pragma unroll
  for (int nf=0; nf<8; nf++) boff[nf] = 8192 + (wn*128 + nf*16 + l16)*32 + swz*8;

  f32x4 acc[8][8];
  #pragma unroll
  for (int i=0;i<8;i++)
    #pragma unroll
    for (int j=0;j<8;j++) acc[i][j] = (f32x4){0.f,0.f,0.f,0.f};

  // prologue: stage tiles 0..3 into bufs 0..3 (8 GLL/tile/wave)
  #pragma unroll
  for (int p=0;p<4;p++){
    #pragma unroll
    for (int j=0;j<4;j++){
      GLL16(sA + (size_t)j*16*D_ + p*32, lds + p*16384 + dA + j*512);
      GLL16(sB + (size_t)j*16*D_ + p*32, lds + p*16384 + 8192 + dA + j*512);
    }
  }
  WAIT_VM16;       // retires 16 oldest = tiles 0,1 (2,3 in flight)
  BARRIER_RAW;

  short8 F0[16], F1[16];
  // read tile-0 fragments into CUR set (F0)
  #pragma unroll
  for (int nf=0; nf<8; nf++) F0[8+nf] = *(const short8*)(lds + boff[nf]);
  #pragma unroll
  for (int mf=0; mf<8; mf++) F0[mf]   = *(const short8*)(lds + aoff[mf]);
  WAIT_LGKM0;
  BARRIER_RAW;     // window 0's stage (tile4 -> buf0) safe vs these reads

#define QKV_WINDOW(KT, CUR, NXT)                                           \
  {                                                                        \
    const int kt_ = (KT);                                                  \
    if (kt_ + 1 < 32){                                                     \
      const short* nb = lds + ((kt_+1)&3)*16384;                           \
      _Pragma("unroll")                                                    \
      for (int nf=0; nf<8; nf++)                                           \
        NXT[8+nf] = *(const short8*)(nb + boff[nf]);                       \
      _Pragma("unroll")                                                    \
      for (int mf=0; mf<8; mf++)                                           \
        NXT[mf] = *(const short8*)(nb + aoff[mf]);                         \
    }                                                                      \
    if (kt_ + 4 < 32){                                                     \
      const int ko = (kt_+4)*32;                                           \
      short* tb = lds + (kt_&3)*16384;                                     \
      _Pragma("unroll")                                                    \
      for (int j=0;j<4;j++){                                               \
        GLL16(sA + (size_t)j*16*D_ + ko, tb + dA + j*512);                 \
        GLL16(sB + (size_t)j*16*D_ + ko, tb + 8192 + dA + j*512);          \
      }                                                                    \
    }                                                                      \
    __builtin_amdgcn_s_setprio(1);                                         \
    _Pragma("unroll")                                                      \
    for (int mf=0; mf<8; mf++)                                             \
      _Pragma("unroll")                                                    \
      for (int nf=0; nf<8; nf++)                                           \
        acc[mf][nf] = __builtin_amdgcn_mfma_f32_16x16x32_bf16(             \
            CUR[mf], CUR[8+nf], acc[mf][nf], 0,0,0);                       \
    __builtin_amdgcn_s_setprio(0);                                         \
    WAIT_LGKM0;                                                            \
    if      (kt_ <= 27) { WAIT_VM16; }                                     \
    else if (kt_ == 28) { WAIT_VM8; }                                      \
    else if (kt_ == 29) { WAIT_VM0; }                                      \
    if (kt_ < 31) BARRIER_RAW;                                             \
  }

  for (int kt = 0; kt < 32; kt += 2){
    QKV_WINDOW(kt,     F0, F1);
    QKV_WINDOW(kt + 1, F1, F0);
  }
#undef QKV_WINDOW

  __syncthreads();

  if (z != 2) {
    const float scale = (z==0) ? QSCALE : 1.0f;
    const float* bias = (z==0) ? bq : bk;
    float bv8[8];
    #pragma unroll
    for (int nf=0; nf<8; nf++) bv8[nf] = bias[n0 + wn*128 + nf*16 + l16];
    short* ep = lds;                    // [128][264] per pass
    #pragma unroll
    for (int p=0; p<2; p++){
      if (wm == p){
        #pragma unroll
        for (int mf=0; mf<8; mf++)
          #pragma unroll
          for (int nf=0; nf<8; nf++)
            #pragma unroll
            for (int i=0; i<4; i++)
              ep[(mf*16 + quad*4 + i)*264 + wn*128 + nf*16 + l16] =
                  f2bf((acc[mf][nf][i] + bv8[nf]) * scale);
      }
      __syncthreads();
      #pragma unroll
      for (int it=0; it<16; it++){
        const int cid = it*256 + t;
        const int row = cid >> 5, cc = cid & 31;
        short8 vv = *(const short8*)(ep + row*264 + cc*8);
        const int m = m0 + p*128 + row, bidx = m >> 11, s = m & 2047;
        const int n = n0 + cc*8, h = n >> 6, dd = n & 63;
        *(short8*)(out + (((size_t)(bidx*H_ + h))*S_ + s)*DK_ + dd) = vv;
      }
      __syncthreads();
    }
  } else {
    float bv8[8];
    #pragma unroll
    for (int nf=0; nf<8; nf++) bv8[nf] = bv[n0 + wn*128 + nf*16 + l16];
    short* ep = lds;                    // [256][136] per pass (n-major)
    #pragma unroll
    for (int p=0; p<2; p++){
      if (wm == p){
        #pragma unroll
        for (int mf=0; mf<8; mf++)
          #pragma unroll
          for (int nf=0; nf<8; nf++)
            #pragma unroll
            for (int i=0; i<4; i++)
              ep[(wn*128 + nf*16 + l16)*136 + mf*16 + quad*4 + i] =
                  f2bf(acc[mf][nf][i] + bv8[nf]);
      }
      __syncthreads();
      #pragma unroll
      for (int it=0; it<16; it++){
        const int cid = it*256 + t;
        const int row = cid >> 4, cc = cid & 15;   // row = n_local 0..255
        short8 vv = *(const short8*)(ep + row*136 + cc*8);
        const int n = n0 + row, h = n >> 6, dd = n & 63;
        const int m0p = m0 + p*128;
        const int bidx = m0p >> 11;
        const int s = (m0p & 2047) + cc*8;
        *(short8*)(out + (((size_t)(bidx*H_ + h))*DK_ + dd)*S_ + s) = vv;
      }
      __syncthreads();
    }
  }
}

// ---------------------------------------------------------------------------
// Kernel 2: flash-style causal attention — 8-wave kv-parity structure.
// (unchanged — R6-verified)
// ---------------------------------------------------------------------------
static __device__ __forceinline__ void attn_steps(
    const int nSteps, const int I0, const int nA, const int q0w,
    const short8* __restrict__ bqv,
    const short* __restrict__ K, const short* __restrict__ VT,
    short (*Kbuf)[4096], short (*Vbuf)[4096],
    const int g, const int w, const int l32, const int h, const int xrow,
    const int row0, const int sc8,
    f32x16& o0, f32x16& o1, float& lsum)
{
  for (int j = 0; j < nSteps; ++j){
    const int I  = I0 + j;                 // global step 0..16
    const int gt = 2*I + g;                // my wave's global tile
    const int kb = (2*j + g)*64;           // keys base within segment
    const bool active = (kb <= q0w + 31);
    const short* Kc = &Kbuf[gt & 3][0];
    const short* Vc = &Vbuf[gt & 3][0];

    // ---- ds_read K/V fragments of my tile ----
    short8 ak[8], vk[8];
    if (active){
      #pragma unroll
      for (int dc=0; dc<4; dc++){
        const int xk = ((dc*2 + h) ^ xrow)*8;
        ak[dc]   = *(const short8*)(Kc + l32*64 + xk);
        ak[4+dc] = *(const short8*)(Kc + (32 + l32)*64 + xk);
        vk[dc]   = *(const short8*)(Vc + l32*64 + xk);
        vk[4+dc] = *(const short8*)(Vc + (32 + l32)*64 + xk);
      }
    }
    WAIT_LGKM0;
    BARRIER_RAW;     // all waves done with bufs (2I)&3,(2I+1)&3

    // ---- prefetch tiles 2I+4, 2I+5 into the buffers just freed ----
    #pragma unroll
    for (int q=0; q<2; q++){
      const int gp = 2*I + 4 + q;
      if (gp < 34){
        const int kbp = (gp < nA ? gp : gp - nA) * 64;
        GLL16(K  + (size_t)(kbp + row0)*DK_ + sc8, &Kbuf[gp & 3][0] + w*512);
        GLL16(VT + (size_t)row0*S_ + kbp + sc8,    &Vbuf[gp & 3][0] + w*512);
      }
    }

    if (active){
      // ---- S^T = K @ Q^T : 8 MFMA ----
      f32x16 s[2];
      #pragma unroll
      for (int e=0;e<16;e++){ s[0][e] = 0.f; s[1][e] = 0.f; }
      #pragma unroll
      for (int dc=0; dc<4; dc++){
        s[0] = __builtin_amdgcn_mfma_f32_32x32x16_bf16(ak[dc],   bqv[dc], s[0], 0,0,0);
        s[1] = __builtin_amdgcn_mfma_f32_32x32x16_bf16(ak[4+dc], bqv[dc], s[1], 0,0,0);
      }

      // ---- causal mask (diagonal tiles only) ----
      if (kb + 63 > q0w) {
        const int qg = q0w + l32;
        #pragma unroll
        for (int r=0; r<16; r++){
          const int k0 = kb + (r&3) + 8*(r>>2) + 4*h;
          if (k0      > qg) s[0][r] = -3.0e38f;
          if (k0 + 32 > qg) s[1][r] = -3.0e38f;
        }
      }

      // ---- p = exp2(s); in-register pack to PV A-fragments (T12) ----
      short8 pf[4];
      #pragma unroll
      for (int mk=0; mk<2; mk++){
        #pragma unroll
        for (int u=0; u<2; u++){
          float p0 = __builtin_amdgcn_exp2f(s[mk][8*u+0]);
          float p1 = __builtin_amdgcn_exp2f(s[mk][8*u+1]);
          float p2 = __builtin_amdgcn_exp2f(s[mk][8*u+2]);
          float p3 = __builtin_amdgcn_exp2f(s[mk][8*u+3]);
          float p4 = __builtin_amdgcn_exp2f(s[mk][8*u+4]);
          float p5 = __builtin_amdgcn_exp2f(s[mk][8*u+5]);
          float p6 = __builtin_amdgcn_exp2f(s[mk][8*u+6]);
          float p7 = __builtin_amdgcn_exp2f(s[mk][8*u+7]);
          lsum += ((p0+p1)+(p2+p3)) + ((p4+p5)+(p6+p7));
          unsigned X0, X1, Y0, Y1;
          asm("v_cvt_pk_bf16_f32 %0, %1, %2" : "=v"(X0) : "v"(p0), "v"(p1));
          asm("v_cvt_pk_bf16_f32 %0, %1, %2" : "=v"(X1) : "v"(p2), "v"(p3));
          asm("v_cvt_pk_bf16_f32 %0, %1, %2" : "=v"(Y0) : "v"(p4), "v"(p5));
          asm("v_cvt_pk_bf16_f32 %0, %1, %2" : "=v"(Y1) : "v"(p6), "v"(p7));
          asm("v_permlane32_swap_b32 %0, %1" : "+v"(X0), "+v"(Y0));
          asm("v_permlane32_swap_b32 %0, %1" : "+v"(X1), "+v"(Y1));
          union { unsigned u4[4]; short8 s8; } pp;
          pp.u4[0] = X0; pp.u4[1] = X1; pp.u4[2] = Y0; pp.u4[3] = Y1;
          pf[mk*2 + u] = pp.s8;
        }
      }

      // ---- PV: o += P @ V : 8 MFMA ----
      #pragma unroll
      for (int kk=0; kk<4; kk++){
        o0 = __builtin_amdgcn_mfma_f32_32x32x16_bf16(pf[kk], vk[kk],   o0, 0,0,0);
        o1 = __builtin_amdgcn_mfma_f32_32x32x16_bf16(pf[kk], vk[4+kk], o1, 0,0,0);
      }
    }

    // ---- counted wait: tiles 2I+2,2I+3 resident before next step ----
    if      (I < 15)  { WAIT_VM4; }
    else if (I == 15) { WAIT_VM0; }
    if (I < 16) BARRIER_RAW;
  }
}

static __device__ __forceinline__ void attn_merge_store(
    float* __restrict__ out, const int bb, const int hh, const int qbase,
    const int w, const int wq, const int lane, const int l32, const int h,
    f32x16& o0, f32x16& o1, float& lsum,
    float (*ms)[64][33])
{
  if (w >= 4){
    #pragma unroll
    for (int e=0; e<16; e++){
      ms[wq][lane][e]    = o0[e];
      ms[wq][lane][16+e] = o1[e];
    }
    ms[wq][lane][32] = lsum;
  }
  WAIT_LGKM0;
  BARRIER_RAW;
  if (w < 4){
    #pragma unroll
    for (int e=0; e<16; e++){
      o0[e] += ms[wq][lane][e];
      o1[e] += ms[wq][lane][16+e];
    }
    float ls = lsum + ms[wq][lane][32];
    float rs = ls + __shfl_xor(ls, 32, 64);
    float linv = 1.0f / rs;
    #pragma unroll
    for (int r=0; r<16; r++){
      const int qrow = (r&3) + 8*(r>>2) + 4*h;
      const float lw = __shfl(linv, qrow, 64);
      float* dst = out + ((size_t)bb*S_ + (qbase + qrow))*D_ + hh*DK_;
      dst[l32]      = o0[r] * lw;
      dst[32 + l32] = o1[r] * lw;
    }
  }
  #pragma unroll
  for (int e=0; e<16; e++){ o0[e] = 0.f; o1[e] = 0.f; }
  lsum = 0.f;
}

__global__ __launch_bounds__(512, 1) void attn(
    const short* __restrict__ qkv, float* __restrict__ out)
{
  const int id = blockIdx.x;                 // 0..255
  const int slot = id >> 3;
  const int bh = (id & 7) + 8*(slot & 3);    // XCD-local bh grouping
  const int p  = slot >> 2;                  // pair index 0..7
  const int nA = 2*p + 2;                    // kv-tiles in segment A (even)

  const short* Q  = qkv + (size_t)bh * (S_*DK_);
  const short* K  = Q + (size_t)(M_*D_);
  const short* VT = qkv + (size_t)(2*M_*D_) + (size_t)bh * (DK_*S_);  // [d][s]

  __shared__ short Kbuf[4][4096];    // 32KB
  __shared__ short Vbuf[4][4096];    // 32KB
  __shared__ float ms[4][64][33];    // 33KB merge scratch (33-pad: bank-free)

  const int t = threadIdx.x;
  const int w = t >> 6, lane = t & 63;       // 8 waves
  const int g = w >> 2, wq = w & 3;          // group, q-slot
  const int l32 = lane & 31, h = lane >> 5;
  const int xrow = l32 & 7;

  const int qA0 = p*128 + wq*32;             // wave q-base, segment A
  const int qB0 = (15-p)*128 + wq*32;        // wave q-base, segment B

  // Q B-frags for BOTH segments, loaded up-front (same rows for both groups).
  short8 bqA[4], bqB[4];
  #pragma unroll
  for (int dc=0; dc<4; dc++){
    bqA[dc] = *(const short8*)(Q + (size_t)(qA0 + l32)*DK_ + dc*16 + h*8);
    bqB[dc] = *(const short8*)(Q + (size_t)(qB0 + l32)*DK_ + dc*16 + h*8);
  }
  #pragma unroll
  for (int dc=0; dc<4; dc++){
    asm volatile("" : "+v"(bqA[dc]));
    asm volatile("" : "+v"(bqB[dc]));
  }

  // staging: 8 waves x 8 rows per tile; lane -> row w*8+(lane>>3),
  // phys chunk lane&7, pre-swizzled source chunk (lane&7)^(lane>>3).
  const int r8   = lane >> 3;
  const int sc8  = ((lane & 7) ^ r8) * 8;
  const int row0 = w*8 + r8;

  // prime tiles 0..3 into bufs 0..3 (2 GLL/tile/wave)
  #pragma unroll
  for (int pt=0; pt<4; pt++){
    const int kb = (pt < nA ? pt : pt - nA) * 64;
    GLL16(K  + (size_t)(kb + row0)*DK_ + sc8, &Kbuf[pt][0] + w*512);
    GLL16(VT + (size_t)row0*S_ + kb + sc8,    &Vbuf[pt][0] + w*512);
  }
  WAIT_VM4;       // retires 8 Q loads + tiles 0,1 (tiles 2,3 in flight)
  BARRIER_RAW;

  f32x16 o0, o1;
  #pragma unroll
  for (int e=0; e<16; e++){ o0[e] = 0.f; o1[e] = 0.f; }
  float lsum = 0.f;
  const int bb = bh >> 4, hh = bh & 15;

  // ---- segment A: steps 0 .. nA/2-1 ----
  attn_steps(nA/2, 0, nA, qA0, bqA, K, VT, Kbuf, Vbuf,
             g, w, l32, h, xrow, row0, sc8, o0, o1, lsum);
  attn_merge_store(out, bb, hh, qA0, w, wq, lane, l32, h, o0, o1, lsum, ms);

  // ---- segment B: steps nA/2 .. 16 ----
  attn_steps(17 - nA/2, nA/2, nA, qB0, bqB, K, VT, Kbuf, Vbuf,
             g, w, l32, h, xrow, row0, sc8, o0, o1, lsum);
  attn_merge_store(out, bb, hh, qB0, w, wq, lane, l32, h, o0, o1, lsum, ms);
}

extern "C" void kernel_launch(void* const* d_in, const int* in_sizes, int n_in,
                              void* d_out, int out_size, void* d_ws, size_t ws_size,
                              hipStream_t stream)
{
  (void)in_sizes; (void)n_in; (void)out_size; (void)ws_size;
  const float* X  = (const float*)d_in[0];
  const float* Wq = (const float*)d_in[1];
  const float* bq = (const float*)d_in[2];
  const float* Wk = (const float*)d_in[3];
  const float* bk = (const float*)d_in[4];
  const float* Wv = (const float*)d_in[5];
  const float* bv = (const float*)d_in[6];
  short* ws  = (short*)d_ws;
  float* out = (float*)d_out;

  dim3 g0(1024, 1, 4);
  cvt_bf16<<<g0, dim3(256,1,1), 0, stream>>>(X, Wq, Wk, Wv, ws);
  dim3 g1(D_/256, M_/256, 3);       // 4 x 16 x 3 = 192 blocks, 256 thr
  qkv_gemm<<<g1, dim3(256,1,1), 0, stream>>>(ws, bq, bk, bv, ws + WS_QKV);
  dim3 g2(256, 1);                  // 256 balanced blocks, 512 thr (8 waves)
  attn<<<g2, dim3(512,1,1), 0, stream>>>(ws + WS_QKV, out);
}

// Round 10
// 155.319 us; speedup vs baseline: 1.7927x; 1.7927x over previous
//
#include <hip/hip_runtime.h>
#include <hip/hip_bf16.h>
#include <stdint.h>

typedef __attribute__((ext_vector_type(8))) short short8;
typedef __attribute__((ext_vector_type(4))) short short4v;
typedef __attribute__((ext_vector_type(4))) float f32x4;
typedef __attribute__((ext_vector_type(16))) float f32x16;

#define B_ 2
#define S_ 2048
#define D_ 1024
#define H_ 16
#define DK_ 64
#define M_ (B_*S_)   // 4096

// workspace layout (in shorts):
//   [0 .. 12582912)          Q | K | VT, each M_*D_ bf16 (VT is [B,H,DK,S])
//   [12582912 .. 16777216)   Xb  bf16 (M_*D_)
//   [16777216 .. 19922944)   Wqb|Wkb|Wvb bf16 (D_*D_ each)
#define WS_QKV   0
#define WS_XB    12582912
#define WS_WB    16777216

// softmax-in-base-2: fold 1/sqrt(DK) * log2(e) into Q
#define QSCALE (0.125f * 1.44269504088896f)

// async global->LDS, 16B per lane; lds base wave-uniform, lane i -> base + i*16
#define GLL16(g, l) __builtin_amdgcn_global_load_lds( \
    (const __attribute__((address_space(1))) void*)(g), \
    (__attribute__((address_space(3))) void*)(l), 16, 0, 0)

#define WAIT_VM0 asm volatile("s_waitcnt vmcnt(0)" ::: "memory")
#define WAIT_VM4 asm volatile("s_waitcnt vmcnt(4)" ::: "memory")
#define WAIT_VM8 asm volatile("s_waitcnt vmcnt(8)" ::: "memory")
#define WAIT_LGKM0 asm volatile("s_waitcnt lgkmcnt(0)" ::: "memory")
#define BARRIER_RAW asm volatile("s_barrier" ::: "memory")

static __device__ __forceinline__ short f2bf(float f){
  union { float f; unsigned u; } x; x.f = f;
  unsigned r = x.u + 0x7fff + ((x.u >> 16) & 1);   // round-to-nearest-even
  return (short)(r >> 16);
}

// ---------------------------------------------------------------------------
// Kernel 0: downcast f32 inputs (X, Wq, Wk, Wv) to bf16 in workspace.
// ---------------------------------------------------------------------------
__global__ __launch_bounds__(256) void cvt_bf16(
    const float* __restrict__ X,  const float* __restrict__ Wq,
    const float* __restrict__ Wk, const float* __restrict__ Wv,
    short* __restrict__ ws)
{
  const int z = blockIdx.z;
  const float* src; short* dst; int n;
  if (z == 0)      { src = X;  dst = ws + WS_XB;               n = M_*D_; }
  else if (z == 1) { src = Wq; dst = ws + WS_WB;               n = D_*D_; }
  else if (z == 2) { src = Wk; dst = ws + WS_WB + D_*D_;       n = D_*D_; }
  else             { src = Wv; dst = ws + WS_WB + 2*(D_*D_);   n = D_*D_; }
  const int stride = gridDim.x * blockDim.x * 4;
  for (int i = (blockIdx.x * blockDim.x + threadIdx.x) * 4; i < n; i += stride) {
    float4 v = *(const float4*)(src + i);
    short4v o;
    o.x = f2bf(v.x); o.y = f2bf(v.y); o.z = f2bf(v.z); o.w = f2bf(v.w);
    *(short4v*)(dst + i) = o;
  }
}

// ---------------------------------------------------------------------------
// Kernel 1: QKV projection — exact R8 version (reverted from R9 spill:
// VGPR=256 + 157MB scratch writes). 256x256 tile, BK=32, 8 waves (2Mx4N),
// 512 thr, cross-tile register double-buffer of fragments.
// ---------------------------------------------------------------------------
__global__ __launch_bounds__(512, 2) void qkv_gemm(
    const short* __restrict__ ws_in,
    const float* __restrict__ bq, const float* __restrict__ bk,
    const float* __restrict__ bv, short* __restrict__ qkv)
{
  const int z = blockIdx.z;
  const short* X  = ws_in + WS_XB;
  const short* Wm = ws_in + WS_WB + (size_t)z * (D_*D_);
  short* out = qkv + (size_t)z * (M_*D_);

  __shared__ __align__(16) short lds[65536];

  const int t = threadIdx.x;            // 0..511
  const int w = t >> 6, lane = t & 63;
  const int quad = lane >> 4, l16 = lane & 15;
  const int wm = w >> 2, wn = w & 3;    // wave grid 2(M) x 4(N)
  const int m0 = blockIdx.y * 256, n0 = blockIdx.x * 256;

  const int rl = t >> 2;
  const int sl = (t & 3) ^ (rl & 3);
  const short* sA0 = X  + (size_t)(m0 + rl) * D_ + sl*8;
  const short* sA1 = sA0 + (size_t)128 * D_;
  const short* sB0 = Wm + (size_t)(n0 + rl) * D_ + sl*8;
  const short* sB1 = sB0 + (size_t)128 * D_;
  const int ldsw = w << 9;

  const int swz = quad ^ (l16 & 3);

  // per-thread fragment offsets (constant; static-indexed -> registers)
  int aoff[8], boff[4];
  #pragma unroll
  for (int mf=0; mf<8; mf++) aoff[mf] = (wm*128 + mf*16 + l16)*32 + swz*8;
  #pragma unroll
  for (int nf=0; nf<4; nf++) boff[nf] = (wn*64 + nf*16 + l16)*32 + swz*8;

  f32x4 acc[8][4];
  #pragma unroll
  for (int i=0;i<8;i++)
    #pragma unroll
    for (int j=0;j<4;j++) acc[i][j] = (f32x4){0.f,0.f,0.f,0.f};

  // prologue: stage tiles 0..3 into bufs 0..3
  #pragma unroll
  for (int p=0;p<4;p++){
    GLL16(sA0 + p*32, lds + p*16384 + ldsw);
    GLL16(sA1 + p*32, lds + p*16384 + 4096 + ldsw);
    GLL16(sB0 + p*32, lds + p*16384 + 8192 + ldsw);
    GLL16(sB1 + p*32, lds + p*16384 + 12288 + ldsw);
  }
  WAIT_VM8;        // tiles 0,1 resident (2,3 in flight)
  BARRIER_RAW;

  short8 F0[12], F1[12];
  // read tile-0 fragments into CUR set (F0); drain before windows begin
  #pragma unroll
  for (int nf=0; nf<4; nf++) F0[8+nf] = *(const short8*)(lds + 8192 + boff[nf]);
  #pragma unroll
  for (int mf=0; mf<8; mf++) F0[mf]   = *(const short8*)(lds + aoff[mf]);
  WAIT_LGKM0;
  BARRIER_RAW;     // window 0's GLL (tile4 -> buf0) safe vs these reads

#define QKV_WINDOW(KT, CUR, NXT)                                           \
  {                                                                        \
    const int kt_ = (KT);                                                  \
    if (kt_ + 1 < 32){                                                     \
      const short* nb = lds + ((kt_+1)&3)*16384;                           \
      _Pragma("unroll")                                                    \
      for (int nf=0; nf<4; nf++)                                           \
        NXT[8+nf] = *(const short8*)(nb + 8192 + boff[nf]);                \
      _Pragma("unroll")                                                    \
      for (int mf=0; mf<8; mf++)                                           \
        NXT[mf] = *(const short8*)(nb + aoff[mf]);                         \
    }                                                                      \
    if (kt_ + 4 < 32){                                                     \
      const int ko = (kt_+4)*32;                                           \
      short* tb = lds + (kt_&3)*16384;                                     \
      GLL16(sA0 + ko, tb + ldsw);                                          \
      GLL16(sA1 + ko, tb + 4096 + ldsw);                                   \
      GLL16(sB0 + ko, tb + 8192 + ldsw);                                   \
      GLL16(sB1 + ko, tb + 12288 + ldsw);                                  \
    }                                                                      \
    __builtin_amdgcn_s_setprio(1);                                         \
    _Pragma("unroll")                                                      \
    for (int mf=0; mf<8; mf++)                                             \
      _Pragma("unroll")                                                    \
      for (int nf=0; nf<4; nf++)                                           \
        acc[mf][nf] = __builtin_amdgcn_mfma_f32_16x16x32_bf16(             \
            CUR[mf], CUR[8+nf], acc[mf][nf], 0,0,0);                       \
    __builtin_amdgcn_s_setprio(0);                                         \
    WAIT_LGKM0;                                                            \
    if      (kt_ <= 27) { WAIT_VM8; }                                      \
    else if (kt_ == 28) { WAIT_VM4; }                                      \
    else if (kt_ == 29) { WAIT_VM0; }                                      \
    if (kt_ < 31) BARRIER_RAW;                                             \
  }

  for (int kt = 0; kt < 32; kt += 2){
    QKV_WINDOW(kt,     F0, F1);
    QKV_WINDOW(kt + 1, F1, F0);
  }
#undef QKV_WINDOW

  __syncthreads();

  if (z != 2) {
    const float scale = (z==0) ? QSCALE : 1.0f;
    const float* bias = (z==0) ? bq : bk;
    float bv4[4];
    #pragma unroll
    for (int nf=0; nf<4; nf++) bv4[nf] = bias[n0 + wn*64 + nf*16 + l16];
    short* ep = lds;
    #pragma unroll
    for (int p=0; p<2; p++){
      if (wm == p){
        #pragma unroll
        for (int mf=0; mf<8; mf++)
          #pragma unroll
          for (int nf=0; nf<4; nf++)
            #pragma unroll
            for (int i=0; i<4; i++)
              ep[(mf*16 + quad*4 + i)*264 + wn*64 + nf*16 + l16] =
                  f2bf((acc[mf][nf][i] + bv4[nf]) * scale);
      }
      __syncthreads();
      #pragma unroll
      for (int it=0; it<8; it++){
        const int cid = it*512 + t;
        const int row = cid >> 5, cc = cid & 31;
        short8 vv = *(const short8*)(ep + row*264 + cc*8);
        const int m = m0 + p*128 + row, bidx = m >> 11, s = m & 2047;
        const int n = n0 + cc*8, h = n >> 6, dd = n & 63;
        *(short8*)(out + (((size_t)(bidx*H_ + h))*S_ + s)*DK_ + dd) = vv;
      }
      __syncthreads();
    }
  } else {
    float bv4[4];
    #pragma unroll
    for (int nf=0; nf<4; nf++) bv4[nf] = bv[n0 + wn*64 + nf*16 + l16];
    short* ep = lds;
    #pragma unroll
    for (int p=0; p<2; p++){
      if (wm == p){
        #pragma unroll
        for (int mf=0; mf<8; mf++)
          #pragma unroll
          for (int nf=0; nf<4; nf++)
            #pragma unroll
            for (int i=0; i<4; i++)
              ep[(wn*64 + nf*16 + l16)*136 + mf*16 + quad*4 + i] =
                  f2bf(acc[mf][nf][i] + bv4[nf]);
      }
      __syncthreads();
      #pragma unroll
      for (int it=0; it<8; it++){
        const int cid = it*512 + t;
        const int row = cid >> 4, cc = cid & 15;
        short8 vv = *(const short8*)(ep + row*136 + cc*8);
        const int n = n0 + row, h = n >> 6, dd = n & 63;
        const int m0p = m0 + p*128;
        const int bidx = m0p >> 11;
        const int s = (m0p & 2047) + cc*8;
        *(short8*)(out + (((size_t)(bidx*H_ + h))*DK_ + dd)*S_ + s) = vv;
      }
      __syncthreads();
    }
  }
}

// ---------------------------------------------------------------------------
// Kernel 2: flash-style causal attention — 8-wave kv-parity structure.
// R10 change: SIX K/V buffers (tiles mod 6; 96KB + 33KB ms = 129KB LDS).
// Prefetch targets (2I+4)%6,(2I+5)%6 — disjoint from this step's read
// buffer (2I+g)%6 and last step's — so the prefetch issues at step TOP,
// the explicit lgkmcnt(0) drain disappears (in-step reads are consumed by
// this step's MFMAs before the closing barrier), and there is ONE barrier
// per step (was 2 + lgkm0). vmcnt ledger unchanged: vmcnt(4) retires tiles
// 2I+2,2I+3 at step end; tail I=15 -> vm0.
// ---------------------------------------------------------------------------
static __device__ __forceinline__ void attn_steps(
    const int nSteps, const int I0, const int nA, const int q0w,
    const short8* __restrict__ bqv,
    const short* __restrict__ K, const short* __restrict__ VT,
    short (*Kbuf)[4096], short (*Vbuf)[4096],
    const int g, const int w, const int l32, const int h, const int xrow,
    const int row0, const int sc8,
    f32x16& o0, f32x16& o1, float& lsum)
{
  int curb = (2*I0 + g) % 6;     // buffer of my wave's tile this step
  int pfb  = (2*I0 + 4) % 6;     // buffer of first prefetch target
  for (int j = 0; j < nSteps; ++j){
    const int I = I0 + j;                  // global step 0..16

    // ---- prefetch tiles 2I+4, 2I+5 at step top (disjoint buffers) ----
    #pragma unroll
    for (int q=0; q<2; q++){
      const int gp = 2*I + 4 + q;
      if (gp < 34){
        const int kbp = (gp < nA ? gp : gp - nA) * 64;
        int b = pfb + q; if (b >= 6) b -= 6;
        GLL16(K  + (size_t)(kbp + row0)*DK_ + sc8, &Kbuf[b][0] + w*512);
        GLL16(VT + (size_t)row0*S_ + kbp + sc8,    &Vbuf[b][0] + w*512);
      }
    }

    const int kb = (2*j + g)*64;           // keys base within segment
    if (kb <= q0w + 31){
      const short* Kc = &Kbuf[curb][0];
      const short* Vc = &Vbuf[curb][0];

      // ---- ds_read K/V fragments (compiler-scheduled lgkm waits) ----
      short8 ak[8], vk[8];
      #pragma unroll
      for (int dc=0; dc<4; dc++){
        const int xk = ((dc*2 + h) ^ xrow)*8;
        ak[dc]   = *(const short8*)(Kc + l32*64 + xk);
        ak[4+dc] = *(const short8*)(Kc + (32 + l32)*64 + xk);
        vk[dc]   = *(const short8*)(Vc + l32*64 + xk);
        vk[4+dc] = *(const short8*)(Vc + (32 + l32)*64 + xk);
      }

      // ---- S^T = K @ Q^T : 8 MFMA ----
      f32x16 s[2];
      #pragma unroll
      for (int e=0;e<16;e++){ s[0][e] = 0.f; s[1][e] = 0.f; }
      #pragma unroll
      for (int dc=0; dc<4; dc++){
        s[0] = __builtin_amdgcn_mfma_f32_32x32x16_bf16(ak[dc],   bqv[dc], s[0], 0,0,0);
        s[1] = __builtin_amdgcn_mfma_f32_32x32x16_bf16(ak[4+dc], bqv[dc], s[1], 0,0,0);
      }

      // ---- causal mask (diagonal tiles only) ----
      if (kb + 63 > q0w) {
        const int qg = q0w + l32;
        #pragma unroll
        for (int r=0; r<16; r++){
          const int k0 = kb + (r&3) + 8*(r>>2) + 4*h;
          if (k0      > qg) s[0][r] = -3.0e38f;
          if (k0 + 32 > qg) s[1][r] = -3.0e38f;
        }
      }

      // ---- p = exp2(s); in-register pack to PV A-fragments (T12) ----
      short8 pf[4];
      #pragma unroll
      for (int mk=0; mk<2; mk++){
        #pragma unroll
        for (int u=0; u<2; u++){
          float p0 = __builtin_amdgcn_exp2f(s[mk][8*u+0]);
          float p1 = __builtin_amdgcn_exp2f(s[mk][8*u+1]);
          float p2 = __builtin_amdgcn_exp2f(s[mk][8*u+2]);
          float p3 = __builtin_amdgcn_exp2f(s[mk][8*u+3]);
          float p4 = __builtin_amdgcn_exp2f(s[mk][8*u+4]);
          float p5 = __builtin_amdgcn_exp2f(s[mk][8*u+5]);
          float p6 = __builtin_amdgcn_exp2f(s[mk][8*u+6]);
          float p7 = __builtin_amdgcn_exp2f(s[mk][8*u+7]);
          lsum += ((p0+p1)+(p2+p3)) + ((p4+p5)+(p6+p7));
          unsigned X0, X1, Y0, Y1;
          asm("v_cvt_pk_bf16_f32 %0, %1, %2" : "=v"(X0) : "v"(p0), "v"(p1));
          asm("v_cvt_pk_bf16_f32 %0, %1, %2" : "=v"(X1) : "v"(p2), "v"(p3));
          asm("v_cvt_pk_bf16_f32 %0, %1, %2" : "=v"(Y0) : "v"(p4), "v"(p5));
          asm("v_cvt_pk_bf16_f32 %0, %1, %2" : "=v"(Y1) : "v"(p6), "v"(p7));
          asm("v_permlane32_swap_b32 %0, %1" : "+v"(X0), "+v"(Y0));
          asm("v_permlane32_swap_b32 %0, %1" : "+v"(X1), "+v"(Y1));
          union { unsigned u4[4]; short8 s8; } pp;
          pp.u4[0] = X0; pp.u4[1] = X1; pp.u4[2] = Y0; pp.u4[3] = Y1;
          pf[mk*2 + u] = pp.s8;
        }
      }

      // ---- PV: o += P @ V : 8 MFMA ----
      #pragma unroll
      for (int kk=0; kk<4; kk++){
        o0 = __builtin_amdgcn_mfma_f32_32x32x16_bf16(pf[kk], vk[kk],   o0, 0,0,0);
        o1 = __builtin_amdgcn_mfma_f32_32x32x16_bf16(pf[kk], vk[4+kk], o1, 0,0,0);
      }
    }

    // ---- counted wait: tiles 2I+2,2I+3 resident before next step ----
    if      (I < 15)  { WAIT_VM4; }
    else if (I == 15) { WAIT_VM0; }
    if (I < 16) BARRIER_RAW;
    curb += 2; if (curb >= 6) curb -= 6;
    pfb  += 2; if (pfb  >= 6) pfb  -= 6;
  }
}

static __device__ __forceinline__ void attn_merge_store(
    float* __restrict__ out, const int bb, const int hh, const int qbase,
    const int w, const int wq, const int lane, const int l32, const int h,
    f32x16& o0, f32x16& o1, float& lsum,
    float (*ms)[64][33])
{
  if (w >= 4){
    #pragma unroll
    for (int e=0; e<16; e++){
      ms[wq][lane][e]    = o0[e];
      ms[wq][lane][16+e] = o1[e];
    }
    ms[wq][lane][32] = lsum;
  }
  WAIT_LGKM0;
  BARRIER_RAW;
  if (w < 4){
    #pragma unroll
    for (int e=0; e<16; e++){
      o0[e] += ms[wq][lane][e];
      o1[e] += ms[wq][lane][16+e];
    }
    float ls = lsum + ms[wq][lane][32];
    float rs = ls + __shfl_xor(ls, 32, 64);
    float linv = 1.0f / rs;
    #pragma unroll
    for (int r=0; r<16; r++){
      const int qrow = (r&3) + 8*(r>>2) + 4*h;
      const float lw = __shfl(linv, qrow, 64);
      float* dst = out + ((size_t)bb*S_ + (qbase + qrow))*D_ + hh*DK_;
      dst[l32]      = o0[r] * lw;
      dst[32 + l32] = o1[r] * lw;
    }
  }
  #pragma unroll
  for (int e=0; e<16; e++){ o0[e] = 0.f; o1[e] = 0.f; }
  lsum = 0.f;
}

__global__ __launch_bounds__(512, 1) void attn(
    const short* __restrict__ qkv, float* __restrict__ out)
{
  const int id = blockIdx.x;                 // 0..255
  const int slot = id >> 3;
  const int bh = (id & 7) + 8*(slot & 3);    // XCD-local bh grouping
  const int p  = slot >> 2;                  // pair index 0..7
  const int nA = 2*p + 2;                    // kv-tiles in segment A (even)

  const short* Q  = qkv + (size_t)bh * (S_*DK_);
  const short* K  = Q + (size_t)(M_*D_);
  const short* VT = qkv + (size_t)(2*M_*D_) + (size_t)bh * (DK_*S_);  // [d][s]

  __shared__ short Kbuf[6][4096];    // 48KB
  __shared__ short Vbuf[6][4096];    // 48KB
  __shared__ float ms[4][64][33];    // 33KB merge scratch (33-pad: bank-free)

  const int t = threadIdx.x;
  const int w = t >> 6, lane = t & 63;       // 8 waves
  const int g = w >> 2, wq = w & 3;          // group, q-slot
  const int l32 = lane & 31, h = lane >> 5;
  const int xrow = l32 & 7;

  const int qA0 = p*128 + wq*32;             // wave q-base, segment A
  const int qB0 = (15-p)*128 + wq*32;        // wave q-base, segment B

  // Q B-frags for BOTH segments, loaded up-front (same rows for both groups).
  short8 bqA[4], bqB[4];
  #pragma unroll
  for (int dc=0; dc<4; dc++){
    bqA[dc] = *(const short8*)(Q + (size_t)(qA0 + l32)*DK_ + dc*16 + h*8);
    bqB[dc] = *(const short8*)(Q + (size_t)(qB0 + l32)*DK_ + dc*16 + h*8);
  }
  #pragma unroll
  for (int dc=0; dc<4; dc++){
    asm volatile("" : "+v"(bqA[dc]));
    asm volatile("" : "+v"(bqB[dc]));
  }

  // staging: 8 waves x 8 rows per tile; lane -> row w*8+(lane>>3),
  // phys chunk lane&7, pre-swizzled source chunk (lane&7)^(lane>>3).
  const int r8   = lane >> 3;
  const int sc8  = ((lane & 7) ^ r8) * 8;
  const int row0 = w*8 + r8;

  // prime tiles 0..3 into bufs 0..3 (2 GLL/tile/wave)
  #pragma unroll
  for (int pt=0; pt<4; pt++){
    const int kb = (pt < nA ? pt : pt - nA) * 64;
    GLL16(K  + (size_t)(kb + row0)*DK_ + sc8, &Kbuf[pt][0] + w*512);
    GLL16(VT + (size_t)row0*S_ + kb + sc8,    &Vbuf[pt][0] + w*512);
  }
  WAIT_VM4;       // retires 8 Q loads + tiles 0,1 (tiles 2,3 in flight)
  BARRIER_RAW;

  f32x16 o0, o1;
  #pragma unroll
  for (int e=0; e<16; e++){ o0[e] = 0.f; o1[e] = 0.f; }
  float lsum = 0.f;
  const int bb = bh >> 4, hh = bh & 15;

  // ---- segment A: steps 0 .. nA/2-1 ----
  attn_steps(nA/2, 0, nA, qA0, bqA, K, VT, Kbuf, Vbuf,
             g, w, l32, h, xrow, row0, sc8, o0, o1, lsum);
  attn_merge_store(out, bb, hh, qA0, w, wq, lane, l32, h, o0, o1, lsum, ms);

  // ---- segment B: steps nA/2 .. 16 ----
  attn_steps(17 - nA/2, nA/2, nA, qB0, bqB, K, VT, Kbuf, Vbuf,
             g, w, l32, h, xrow, row0, sc8, o0, o1, lsum);
  attn_merge_store(out, bb, hh, qB0, w, wq, lane, l32, h, o0, o1, lsum, ms);
}

extern "C" void kernel_launch(void* const* d_in, const int* in_sizes, int n_in,
                              void* d_out, int out_size, void* d_ws, size_t ws_size,
                              hipStream_t stream)
{
  (void)in_sizes; (void)n_in; (void)out_size; (void)ws_size;
  const float* X  = (const float*)d_in[0];
  const float* Wq = (const float*)d_in[1];
  const float* bq = (const float*)d_in[2];
  const float* Wk = (const float*)d_in[3];
  const float* bk = (const float*)d_in[4];
  const float* Wv = (const float*)d_in[5];
  const float* bv = (const float*)d_in[6];
  short* ws  = (short*)d_ws;
  float* out = (float*)d_out;

  dim3 g0(1024, 1, 4);
  cvt_bf16<<<g0, dim3(256,1,1), 0, stream>>>(X, Wq, Wk, Wv, ws);
  dim3 g1(D_/256, M_/256, 3);       // 4 x 16 x 3 = 192 blocks, 512 thr
  qkv_gemm<<<g1, dim3(512,1,1), 0, stream>>>(ws, bq, bk, bv, ws + WS_QKV);
  dim3 g2(256, 1);                  // 256 balanced blocks, 512 thr (8 waves)
  attn<<<g2, dim3(512,1,1), 0, stream>>>(ws + WS_QKV, out);
}